// Round 5
// baseline (276.090 us; speedup 1.0000x reference)
//
#include <hip/hip_runtime.h>
#include <stdint.h>

// ---- types ----
typedef __bf16 bf16x8 __attribute__((ext_vector_type(8)));
typedef __bf16 bf16x4 __attribute__((ext_vector_type(4)));
typedef short  s16x4  __attribute__((ext_vector_type(4)));
typedef float  f32x4  __attribute__((ext_vector_type(4)));
typedef unsigned int u32x4 __attribute__((ext_vector_type(4)));
typedef unsigned short u16;

__device__ __forceinline__ u16 f2bf(float f) {
    union { float f; unsigned u; } v; v.f = f;
    unsigned r = v.u + 0x7fffu + ((v.u >> 16) & 1u);
    return (u16)(r >> 16);
}

// packed 2x f32 -> bf16 (RNE); [15:0]=a, [31:16]=b
__device__ __forceinline__ unsigned pk_bf16(float a, float b) {
#if __has_builtin(__builtin_amdgcn_cvt_pk_bf16_f32)
    typedef __bf16 bf16x2_t __attribute__((ext_vector_type(2)));
    bf16x2_t r = __builtin_amdgcn_cvt_pk_bf16_f32(a, b);
    return __builtin_bit_cast(unsigned, r);
#else
    return (unsigned)f2bf(a) | ((unsigned)f2bf(b) << 16);
#endif
}

__device__ __forceinline__ bf16x8 ld_frag(const u16* p) {
    u32x4 u = *(const u32x4*)p;
    return __builtin_bit_cast(bf16x8, u);
}

// K=16 bf16 MFMA (C/D layout == B k-layout: the in-register P transform)
__device__ __forceinline__ f32x4 mfma16(bf16x4 a, bf16x4 b, f32x4 c) {
#if __has_builtin(__builtin_amdgcn_mfma_f32_16x16x16_bf16)
    return __builtin_amdgcn_mfma_f32_16x16x16_bf16(a, b, c, 0, 0, 0);
#else
    return __builtin_amdgcn_mfma_f32_16x16x16bf16_1k(
        __builtin_bit_cast(s16x4, a), __builtin_bit_cast(s16x4, b), c, 0, 0, 0);
#endif
}

// async global->LDS, 16B per lane; LDS dest = wave-uniform base + lane*16
__device__ __forceinline__ void gload16(const u16* g, u16* l) {
    __builtin_amdgcn_global_load_lds(
        (__attribute__((address_space(1))) void*)g,
        (__attribute__((address_space(3))) void*)l,
        16, 0, 0);
}

#define ATT_CSC 0.18033688011112042f  // (1/sqrt(64)) * log2(e)

// ---- fp32 -> bf16 convert (vec4) ----
__global__ __launch_bounds__(256) void cvt_f32_bf16(const float* __restrict__ in,
                                                    u16* __restrict__ out, int n4) {
    int i = blockIdx.x * 256 + threadIdx.x;
    if (i < n4) {
        float4 v = ((const float4*)in)[i];
        uint2 o;
        o.x = pk_bf16(v.x, v.y);
        o.y = pk_bf16(v.z, v.w);
        ((uint2*)out)[i] = o;
    }
}

// ---- 128x128xBK32 bf16 MFMA GEMM, Y = A @ W^T + bias, global_load_lds staging ----
__global__ __launch_bounds__(256) void gemm_bt(
    int mode, int ncols,
    const u16* __restrict__ A,
    const u16* __restrict__ W,
    const float* __restrict__ bias,
    const float* __restrict__ xres,
    const float* __restrict__ theta,
    u16* __restrict__ out_bf,
    u16* __restrict__ qo, u16* __restrict__ ko, u16* __restrict__ vTo,
    float* __restrict__ out_f)
{
    __shared__ alignas(16) u16 As[128 * 32];
    __shared__ alignas(16) u16 Bs[128 * 32];
    const int tid  = threadIdx.x;
    const int wave = tid >> 6, lane = tid & 63;
    const int lquad = lane >> 4, lcol = lane & 15;
    const int wr = (wave >> 1) * 64, wc = (wave & 1) * 64;
    const int rowb = blockIdx.x * 128, colb = blockIdx.y * 128;

    const u16* src  = (wave & 2) ? W : A;
    const int  rbase = (wave & 2) ? colb : rowb;
    u16* dst = ((wave & 2) ? Bs : As) + (wave & 1) * 64 * 32;
    const u16* gsrc = src + (size_t)(rbase + (wave & 1) * 64 + (lane >> 2)) * 1024 + (lane & 3) * 8;

    f32x4 zero4 = {0.f, 0.f, 0.f, 0.f};
    f32x4 acc[4][4];
#pragma unroll
    for (int i = 0; i < 4; i++)
#pragma unroll
        for (int j = 0; j < 4; j++) acc[i][j] = zero4;

    for (int k0 = 0; k0 < 1024; k0 += 32) {
        __syncthreads();
#pragma unroll
        for (int i = 0; i < 4; i++)
            gload16(gsrc + (size_t)(i * 16) * 1024 + k0, dst + i * 16 * 32);
        __syncthreads();
        bf16x8 af[4], bfr[4];
#pragma unroll
        for (int t = 0; t < 4; t++) af[t]  = ld_frag(As + (wr + t * 16 + lcol) * 32 + lquad * 8);
#pragma unroll
        for (int t = 0; t < 4; t++) bfr[t] = ld_frag(Bs + (wc + t * 16 + lcol) * 32 + lquad * 8);
#pragma unroll
        for (int i = 0; i < 4; i++)
#pragma unroll
            for (int j = 0; j < 4; j++)
                acc[i][j] = __builtin_amdgcn_mfma_f32_16x16x32_bf16(af[i], bfr[j], acc[i][j], 0, 0, 0);
    }

#pragma unroll
    for (int i = 0; i < 4; i++) {
#pragma unroll
        for (int j = 0; j < 4; j++) {
            int gcol = colb + wc + j * 16 + lcol;
            float bsv = bias[gcol];
            int grow0 = rowb + wr + i * 16 + lquad * 4;
            if (mode == 0) {
#pragma unroll
                for (int r = 0; r < 4; r++) {
                    size_t idx = (size_t)(grow0 + r) * 1024 + gcol;
                    float val = acc[i][j][r] + bsv;
                    out_bf[idx] = f2bf(xres[idx] + 0.1f * (val * theta[gcol]));
                }
            } else if (mode == 1) {
                int three = gcol >> 10, rem = gcol & 1023;
                int h = rem >> 6, d = rem & 63;
                int b = grow0 >> 11, nn = grow0 & 2047;
                int bh = b * 16 + h;
                if (three == 2) {
                    ushort4 o;
                    o.x = f2bf(acc[i][j][0] + bsv);
                    o.y = f2bf(acc[i][j][1] + bsv);
                    o.z = f2bf(acc[i][j][2] + bsv);
                    o.w = f2bf(acc[i][j][3] + bsv);
                    *(ushort4*)(vTo + ((size_t)bh * 64 + d) * 2048 + nn) = o;
                } else if (three == 0) {
#pragma unroll
                    for (int r = 0; r < 4; r++)
                        qo[((size_t)bh * 2048 + nn + r) * 64 + d] = f2bf((acc[i][j][r] + bsv) * ATT_CSC);
                } else {
#pragma unroll
                    for (int r = 0; r < 4; r++)
                        ko[((size_t)bh * 2048 + nn + r) * 64 + d] = f2bf(acc[i][j][r] + bsv);
                }
            } else {
#pragma unroll
                for (int r = 0; r < 4; r++)
                    out_f[(size_t)(grow0 + r) * 1024 + gcol] = acc[i][j][r] + bsv;
            }
        }
    }
}

// ---- flash attention: wave-owns-j; S^T = K Q'^T (K=32), O^T += V^T P^T (K=16) ----
// block: 64 q-rows; j-tile 64 (16 per wave); grid (32, 32)
__global__ __launch_bounds__(256) void attn_kernel(
    const u16* __restrict__ q,   // [B*H, N, D] (pre-scaled by csc)
    const u16* __restrict__ k,   // [B*H, N, D]
    const u16* __restrict__ vT,  // [B*H, D, N]
    u16* __restrict__ attnout)   // [B, N, H*D]
{
    __shared__ alignas(16) unsigned char smem[17408];
    u16*   Ks = (u16*)smem;              // 8KB [db2][j64][32]
    u16*   Vs = (u16*)(smem + 8192);     // 8KB [jb2][d64][32]
    float* Rs = (float*)smem;            // 16KB (reused post-loop): [w4][q64][d16]
    float* Ls = (float*)(smem + 16384);  // 1KB: [w4][q64]

    const int tid  = threadIdx.x;
    const int wave = tid >> 6, lane = tid & 63;
    const int lquad = lane >> 4, lcol = lane & 15;
    const int bh   = blockIdx.y;
    const int q0   = blockIdx.x * 64;

    // Q as B-operand (K=32): n=q=lcol, k=d
    bf16x8 qf[4][2];
#pragma unroll
    for (int qh = 0; qh < 4; qh++)
#pragma unroll
        for (int db = 0; db < 2; db++)
            qf[qh][db] = ld_frag(q + ((size_t)bh * 2048 + q0 + qh * 16 + lcol) * 64 + db * 32 + lquad * 8);

    float lrun[4] = {0.f, 0.f, 0.f, 0.f};
    f32x4 zero4 = {0.f, 0.f, 0.f, 0.f};
    f32x4 oacc[4][4];   // [qh][dt]: col q=lcol, row d=dt*16+lquad*4+r (partial over my js)
#pragma unroll
    for (int qh = 0; qh < 4; qh++)
#pragma unroll
        for (int dt = 0; dt < 4; dt++) oacc[qh][dt] = zero4;

    // staging: wave 0,1 -> K halves (d-split db); wave 2,3 -> V^T halves (j-split jb)
    const int sb = wave & 1;
    const int srow = lane >> 2, scol = (lane & 3) * 8;
    const u16* gK = k  + ((size_t)bh * 2048 + srow) * 64 + sb * 32 + scol;
    const u16* gV = vT + ((size_t)bh * 64 + srow) * 2048 + sb * 32 + scol;
    u16* ldst = ((wave & 2) ? Vs : Ks) + sb * 64 * 32;

    // my j-slice: j = wave*16 + lquad*4 + r (within tile)
    const int vjb = wave >> 1;                    // which Vs half my js live in
    const int vjo = (wave & 1) * 16 + lquad * 4;  // offset within half

    for (int j0 = 0; j0 < 2048; j0 += 64) {
        __syncthreads();
        if ((wave & 2) == 0) {
#pragma unroll
            for (int i = 0; i < 4; i++)
                gload16(gK + (size_t)(j0 + i * 16) * 64, ldst + i * 16 * 32);
        } else {
#pragma unroll
            for (int i = 0; i < 4; i++)
                gload16(gV + (size_t)(i * 16) * 2048 + j0, ldst + i * 16 * 32);
        }
        __syncthreads();

        // S^T: my 16 js x 64 q. A = K rows (m=j), B = Q (n=q)
        bf16x8 kf[2];
#pragma unroll
        for (int db = 0; db < 2; db++)
            kf[db] = ld_frag(Ks + db * 2048 + (wave * 16 + lcol) * 32 + lquad * 8);
        f32x4 sacc[4];
#pragma unroll
        for (int qh = 0; qh < 4; qh++) sacc[qh] = zero4;
#pragma unroll
        for (int qh = 0; qh < 4; qh++)
#pragma unroll
            for (int db = 0; db < 2; db++)
                sacc[qh] = __builtin_amdgcn_mfma_f32_16x16x32_bf16(kf[db], qf[qh][db], sacc[qh], 0, 0, 0);

        // p = exp2(s) in-register; C/D row (lquad*4+r) == B-operand k (lquad*4+i)
        bf16x4 pf[4];
#pragma unroll
        for (int qh = 0; qh < 4; qh++) {
            float p0 = __builtin_amdgcn_exp2f(sacc[qh][0]);
            float p1 = __builtin_amdgcn_exp2f(sacc[qh][1]);
            float p2 = __builtin_amdgcn_exp2f(sacc[qh][2]);
            float p3 = __builtin_amdgcn_exp2f(sacc[qh][3]);
            lrun[qh] += (p0 + p1) + (p2 + p3);
            uint2 u;
            u.x = pk_bf16(p0, p1);
            u.y = pk_bf16(p2, p3);
            pf[qh] = __builtin_bit_cast(bf16x4, u);
        }

        // O^T += V^T P^T over my 16 js (K=16 MFMA). A = V^T (m=d, k=j)
#pragma unroll
        for (int dt = 0; dt < 4; dt++) {
            const u16* vp = Vs + vjb * 2048 + (dt * 16 + lcol) * 32 + vjo;
            bf16x4 vf = __builtin_bit_cast(bf16x4, *(const uint2*)vp);
#pragma unroll
            for (int qh = 0; qh < 4; qh++)
                oacc[qh][dt] = mfma16(vf, pf[qh], oacc[qh][dt]);
        }
    }

    // l: reduce over lquad in-wave; stash per-wave partials
    float lw[4];
#pragma unroll
    for (int qh = 0; qh < 4; qh++) {
        float l = lrun[qh];
        l += __shfl_xor(l, 16, 64);
        l += __shfl_xor(l, 32, 64);
        lw[qh] = l;
    }
    if (lquad == 0) {
#pragma unroll
        for (int qh = 0; qh < 4; qh++)
            Ls[wave * 64 + qh * 16 + lcol] = lw[qh];
    }

    // cross-wave O reduction: 4 rounds through 16KB LDS; wave t keeps dt=t
    f32x4 fin[4];
#pragma unroll
    for (int qh = 0; qh < 4; qh++) fin[qh] = zero4;
    for (int t = 0; t < 4; t++) {
        __syncthreads();   // frag reads (round 0: K/V reads) done before overwrite
#pragma unroll
        for (int qh = 0; qh < 4; qh++)
            *(f32x4*)&Rs[(wave * 64 + qh * 16 + lcol) * 16 + lquad * 4] = oacc[qh][t];
        __syncthreads();
        if (wave == t) {
#pragma unroll
            for (int qh = 0; qh < 4; qh++) {
                f32x4 s = *(const f32x4*)&Rs[(0 * 64 + qh * 16 + lcol) * 16 + lquad * 4];
#pragma unroll
                for (int w = 1; w < 4; w++)
                    s += *(const f32x4*)&Rs[(w * 64 + qh * 16 + lcol) * 16 + lquad * 4];
                fin[qh] = s;
            }
        }
    }
    __syncthreads();

    // epilogue: wave t owns d-rows [16t,16t+16); out[b, n=q, h*64+d]
    const int b = bh >> 4, h = bh & 15;
#pragma unroll
    for (int qh = 0; qh < 4; qh++) {
        float l = Ls[0 * 64 + qh * 16 + lcol] + Ls[1 * 64 + qh * 16 + lcol]
                + Ls[2 * 64 + qh * 16 + lcol] + Ls[3 * 64 + qh * 16 + lcol];
        float inv = 1.0f / l;
        const int n = q0 + qh * 16 + lcol;
        uint2 o;
        o.x = pk_bf16(fin[qh][0] * inv, fin[qh][1] * inv);
        o.y = pk_bf16(fin[qh][2] * inv, fin[qh][3] * inv);
        *(uint2*)(attnout + ((size_t)b * 2048 + n) * 1024 + h * 64 + wave * 16 + lquad * 4) = o;
    }
}

extern "C" void kernel_launch(void* const* d_in, const int* in_sizes, int n_in,
                              void* d_out, int out_size, void* d_ws, size_t ws_size,
                              hipStream_t stream) {
    const float* x     = (const float*)d_in[0];
    const float* theta = (const float*)d_in[1];
    const float* Wg    = (const float*)d_in[2];
    const float* bg    = (const float*)d_in[3];
    const float* Wqkv  = (const float*)d_in[4];
    const float* bqkv  = (const float*)d_in[5];
    const float* Wproj = (const float*)d_in[6];
    const float* bproj = (const float*)d_in[7];
    float* out = (float*)d_out;

    unsigned char* ws = (unsigned char*)d_ws;
    const size_t MB = 1ull << 20;
    u16* x_bf     = (u16*)(ws + 0);
    u16* Wg_bf    = (u16*)(ws + 8 * MB);
    u16* Wqkv_bf  = (u16*)(ws + 10 * MB);
    u16* Wproj_bf = (u16*)(ws + 16 * MB);
    u16* xg_bf    = (u16*)(ws + 18 * MB);
    u16* q_bf     = (u16*)(ws + 26 * MB);
    u16* k_bf     = (u16*)(ws + 34 * MB);
    u16* vT_bf    = (u16*)(ws + 42 * MB);
    u16* ao_bf    = (u16*)(ws + 50 * MB);

    dim3 blk(256);
    cvt_f32_bf16<<<1024, blk, 0, stream>>>(x,     x_bf,     262144);
    cvt_f32_bf16<<<1024, blk, 0, stream>>>(Wg,    Wg_bf,    262144);
    cvt_f32_bf16<<<3072, blk, 0, stream>>>(Wqkv,  Wqkv_bf,  786432);
    cvt_f32_bf16<<<1024, blk, 0, stream>>>(Wproj, Wproj_bf, 262144);
    cvt_f32_bf16<<<3072, blk, 0, stream>>>(x + 1048576, x_bf + 1048576, 786432);

    gemm_bt<<<dim3(32, 8), blk, 0, stream>>>(0, 1024, x_bf, Wg_bf, bg,
                                             x, theta, xg_bf,
                                             nullptr, nullptr, nullptr, nullptr);
    gemm_bt<<<dim3(32, 24), blk, 0, stream>>>(1, 3072, xg_bf, Wqkv_bf, bqkv,
                                              nullptr, nullptr, nullptr,
                                              q_bf, k_bf, vT_bf, nullptr);
    attn_kernel<<<dim3(32, 32), blk, 0, stream>>>(q_bf, k_bf, vT_bf, ao_bf);
    gemm_bt<<<dim3(32, 8), blk, 0, stream>>>(2, 1024, ao_bf, Wproj_bf, bproj,
                                             nullptr, nullptr, nullptr,
                                             nullptr, nullptr, nullptr, out);
}